// Round 1
// baseline (496.316 us; speedup 1.0000x reference)
//
#include <hip/hip_runtime.h>
#include <math.h>

// ---------------------------------------------------------------------------
// MultiLoss + JSD fused pipeline.
// Inputs : data_encoded [B,11] f32, data_decoded [B,168] f32,
//          data_true [B,168] f32 (one-hot CE blocks), label_true [B,1] f32,
//          batch_size (scalar, unused; B taken from in_sizes[3]).
// Output : [multi, mse, ce, 0.1*kld] f32.
// ---------------------------------------------------------------------------

#define BINS 800
#define NHCOLS 10

// workspace layout (uint32 indices)
#define MIN_OFF 0        // 11 ordered-uint mins
#define MAX_OFF 16       // 11 ordered-uint maxs
#define CNT_OFF 32       // male, female counts
#define SUM_OFF 34       // mse_sum, ce_sum (float)
#define MH_OFF  64       // 8000 male hist
#define FH_OFF  8064     // 8000 female hist
#define WS_U32_TOTAL 16064

// monotone float <-> ordered-uint mapping (for atomicMin/Max on floats)
__device__ __forceinline__ unsigned f2ord(float f) {
  unsigned u = __float_as_uint(f);
  return (u & 0x80000000u) ? ~u : (u | 0x80000000u);
}
__device__ __forceinline__ float ord2f(unsigned e) {
  return __uint_as_float((e & 0x80000000u) ? (e & 0x7FFFFFFFu) : ~e);
}

__global__ void k_init(unsigned* __restrict__ ws) {
  int i = blockIdx.x * blockDim.x + threadIdx.x;
  if (i < WS_U32_TOTAL) ws[i] = (i < 11) ? 0xFFFFFFFFu : 0u;
}

// per-column min/max of data_encoded + male/female counts from label.
// grid*block must be a multiple of 11 so each thread's flat index keeps a
// constant column (coalesced loads, single min/max register pair per thread).
__global__ __launch_bounds__(256) void k_minmax(const float* __restrict__ enc,
                                                const float* __restrict__ lab,
                                                unsigned* __restrict__ ws, int B) {
  const int tid    = blockIdx.x * blockDim.x + threadIdx.x;
  const int stride = gridDim.x * blockDim.x;   // 352*256 = 90112 = 11*8192
  const int c      = tid % 11;
  unsigned mn = 0xFFFFFFFFu, mx = 0u;
  const long long total = (long long)B * 11;
  for (long long i = tid; i < total; i += stride) {
    unsigned e = f2ord(enc[i]);
    mn = mn < e ? mn : e;
    mx = mx > e ? mx : e;
  }
  __shared__ unsigned smn[11], smx[11], scnt[2];
  if (threadIdx.x < 11) { smn[threadIdx.x] = 0xFFFFFFFFu; smx[threadIdx.x] = 0u; }
  if (threadIdx.x < 2)  scnt[threadIdx.x] = 0u;
  __syncthreads();
  atomicMin(&smn[c], mn);
  atomicMax(&smx[c], mx);
  unsigned m = 0, f = 0;
  for (int i = tid; i < B; i += stride) {
    float v = lab[i];
    m += (v == 0.0f);
    f += (v == 1.0f);
  }
  atomicAdd(&scnt[0], m);
  atomicAdd(&scnt[1], f);
  __syncthreads();
  if (threadIdx.x < 11) {
    atomicMin(&ws[MIN_OFF + threadIdx.x], smn[threadIdx.x]);
    atomicMax(&ws[MAX_OFF + threadIdx.x], smx[threadIdx.x]);
  }
  if (threadIdx.x == 11) atomicAdd(&ws[CNT_OFF + 0], scnt[0]);
  if (threadIdx.x == 12) atomicAdd(&ws[CNT_OFF + 1], scnt[1]);
}

// gendered histograms: LDS hist packed male(lo16)/female(hi16); safe because
// rows/block <= 2048 < 65536. Flush nonzero bins with global atomics.
__global__ __launch_bounds__(256) void k_hist(const float* __restrict__ enc,
                                              const float* __restrict__ lab,
                                              unsigned* __restrict__ ws, int B) {
  __shared__ unsigned h[NHCOLS * BINS];
  for (int i = threadIdx.x; i < NHCOLS * BINS; i += blockDim.x) h[i] = 0u;
  float mn[NHCOLS], rng[NHCOLS];
#pragma unroll
  for (int c = 0; c < NHCOLS; ++c) {
    float lo = ord2f(ws[MIN_OFF + c]);
    float hi = ord2f(ws[MAX_OFF + c]);
    mn[c] = lo; rng[c] = hi - lo;
  }
  __syncthreads();
  const int tid    = blockIdx.x * blockDim.x + threadIdx.x;
  const int stride = gridDim.x * blockDim.x;
  for (int r = tid; r < B; r += stride) {
    float lv = lab[r];
    unsigned add = (lv == 0.0f) ? 1u : ((lv == 1.0f) ? 0x10000u : 0u);
    if (add) {
      const float* row = enc + (long long)r * 11;
#pragma unroll
      for (int c = 0; c < NHCOLS; ++c) {
        float t = (row[c] - mn[c]) / rng[c];   // IEEE div, matches numpy
        int b = (int)floorf(t * 800.0f);
        b = b < 0 ? 0 : (b > BINS - 1 ? BINS - 1 : b);
        atomicAdd(&h[c * BINS + b], add);
      }
    }
  }
  __syncthreads();
  for (int i = threadIdx.x; i < NHCOLS * BINS; i += blockDim.x) {
    unsigned v = h[i];
    unsigned lo = v & 0xFFFFu, hi = v >> 16;
    if (lo) atomicAdd(&ws[MH_OFF + i], lo);
    if (hi) atomicAdd(&ws[FH_OFF + i], hi);
  }
}

// CE head: data_true slice is exact one-hot => x[label] = dot(t, x).
// ce = logsumexp(x) - dot(t, x). Slice buffered in registers (max W=24).
template<int S, int E>
__device__ __forceinline__ float ce_slice(const float* __restrict__ dR,
                                          const float* __restrict__ tR) {
  constexpr int W = E - S;
  float d[W];
  float m = -3.402823466e38f;
#pragma unroll
  for (int j = 0; j < W; ++j) { d[j] = dR[S + j]; m = fmaxf(m, d[j]); }
  float dot = 0.0f;
#pragma unroll
  for (int j = 0; j < W; ++j) dot = fmaf(tR[S + j], d[j], dot);
  float s = 0.0f;
#pragma unroll
  for (int j = 0; j < W; ++j) s += __expf(d[j] - m);
  return m + __logf(s) - dot;
}

// one thread per row; single ordered sweep: CE slices + MSE gap columns
// cover all 168 columns exactly once each.
__global__ __launch_bounds__(256) void k_main(const float* __restrict__ dec,
                                              const float* __restrict__ tru,
                                              float* __restrict__ wsf, int B) {
  int r = blockIdx.x * blockDim.x + threadIdx.x;
  float mse = 0.0f, ce = 0.0f;
  if (r < B) {
    const float* dR = dec + (long long)r * 168;
    const float* tR = tru + (long long)r * 168;
#define MSEC(c) { float df = dR[c] - tR[c]; mse = fmaf(df, df, mse); }
    MSEC(0)
    ce += ce_slice<1, 10>(dR, tR);
    MSEC(10) MSEC(11)
    ce += ce_slice<12, 29>(dR, tR);
    MSEC(29)
    ce += ce_slice<30, 33>(dR, tR);
    ce += ce_slice<33, 40>(dR, tR);
    ce += ce_slice<40, 64>(dR, tR);
    ce += ce_slice<64, 79>(dR, tR);
    ce += ce_slice<79, 84>(dR, tR);
    ce += ce_slice<84, 94>(dR, tR);
    ce += ce_slice<94, 96>(dR, tR);
    ce += ce_slice<96, 99>(dR, tR);
    ce += ce_slice<99, 105>(dR, tR);
    ce += ce_slice<105, 113>(dR, tR);
    MSEC(113) MSEC(114) MSEC(115)
    ce += ce_slice<116, 122>(dR, tR);
    ce += ce_slice<122, 128>(dR, tR);
    ce += ce_slice<128, 151>(dR, tR);
    ce += ce_slice<151, 159>(dR, tR);
    MSEC(159)
    ce += ce_slice<160, 165>(dR, tR);
    MSEC(165) MSEC(166) MSEC(167)
#undef MSEC
  }
  __shared__ float sm[4], sc[4];
  int lane = threadIdx.x & 63, wid = threadIdx.x >> 6;
#pragma unroll
  for (int off = 32; off > 0; off >>= 1) {
    mse += __shfl_down(mse, off, 64);
    ce  += __shfl_down(ce, off, 64);
  }
  if (lane == 0) { sm[wid] = mse; sc[wid] = ce; }
  __syncthreads();
  if (threadIdx.x == 0) {
    atomicAdd(&wsf[SUM_OFF + 0], sm[0] + sm[1] + sm[2] + sm[3]);
    atomicAdd(&wsf[SUM_OFF + 1], sc[0] + sc[1] + sc[2] + sc[3]);
  }
}

__global__ __launch_bounds__(256) void k_final(const unsigned* __restrict__ ws,
                                               float* __restrict__ out, int B) {
  const float* wsf = (const float*)ws;
  float male   = (float)ws[CNT_OFF + 0];
  float female = (float)ws[CNT_OFF + 1];
  float local = 0.0f;
  for (int i = threadIdx.x; i < NHCOLS * BINS; i += blockDim.x) {
    float mh  = (float)ws[MH_OFF + i] / male;
    float fh  = (float)ws[FH_OFF + i] / female;
    float mid = 0.5f * (mh + fh);
    if (mh > 0.0f) local += mh * logf((mh + 1e-12f) / (mid + 1e-12f));
    if (fh > 0.0f) local += fh * logf((fh + 1e-12f) / (mid + 1e-12f));
  }
  __shared__ float s[4];
  int lane = threadIdx.x & 63, wid = threadIdx.x >> 6;
#pragma unroll
  for (int off = 32; off > 0; off >>= 1) local += __shfl_down(local, off, 64);
  if (lane == 0) s[wid] = local;
  __syncthreads();
  if (threadIdx.x == 0) {
    float kld   = 0.5f * (s[0] + s[1] + s[2] + s[3]);
    float mse   = wsf[SUM_OFF + 0] / (float)B;
    float ce    = wsf[SUM_OFF + 1] / (float)B;
    float multi = 0.9f * (mse + ce) + 0.1f * kld;
    out[0] = multi;
    out[1] = mse;
    out[2] = ce;
    out[3] = 0.1f * kld;
  }
}

extern "C" void kernel_launch(void* const* d_in, const int* in_sizes, int n_in,
                              void* d_out, int out_size, void* d_ws, size_t ws_size,
                              hipStream_t stream) {
  (void)n_in; (void)out_size; (void)ws_size;
  const float* enc = (const float*)d_in[0];
  const float* dec = (const float*)d_in[1];
  const float* tru = (const float*)d_in[2];
  const float* lab = (const float*)d_in[3];
  const int B = in_sizes[3];                 // label_true is [B,1]
  unsigned* ws = (unsigned*)d_ws;
  float* out = (float*)d_out;

  hipLaunchKernelGGL(k_init, dim3((WS_U32_TOTAL + 255) / 256), dim3(256), 0, stream, ws);
  // 352*256 = 90112 is a multiple of 11 (column-constant stride)
  hipLaunchKernelGGL(k_minmax, dim3(352), dim3(256), 0, stream, enc, lab, ws, B);
  hipLaunchKernelGGL(k_hist, dim3(128), dim3(256), 0, stream, enc, lab, ws, B);
  hipLaunchKernelGGL(k_main, dim3((B + 255) / 256), dim3(256), 0, stream,
                     dec, tru, (float*)ws, B);
  hipLaunchKernelGGL(k_final, dim3(1), dim3(256), 0, stream, ws, out, B);
}